// Round 8
// baseline (1066.320 us; speedup 1.0000x reference)
//
#include <hip/hip_runtime.h>
#include <math.h>

#define NG 32
#define NK 1024
#define ND 64
#define NB 4096
#define KSPLIT 4
#define KCHUNK (NK / KSPLIT)

// ws layout (floats): [0 .. NG*NK) c2 | counts(int)[NK] | loss sum

// c2 precompute + buffer init fused (disjoint writes, both done before vq_main).
__global__ void vq_c2(const float* __restrict__ cb, float* __restrict__ c2,
                      int* __restrict__ counts, float* __restrict__ losssum) {
    int i = blockIdx.x * blockDim.x + threadIdx.x;
    if (i < NK) counts[i] = 0;
    if (i == 0) *losssum = 0.f;
    if (i >= NG * NK) return;
    const float* c = cb + (size_t)i * ND;
    float s0 = 0.f, s1 = 0.f, s2 = 0.f, s3 = 0.f;
#pragma unroll
    for (int d = 0; d < ND; d += 4) {
        float4 v = *reinterpret_cast<const float4*>(c + d);
        s0 = fmaf(v.x, v.x, s0);
        s1 = fmaf(v.y, v.y, s1);
        s2 = fmaf(v.z, v.z, s2);
        s3 = fmaf(v.w, v.w, s3);
    }
    c2[i] = (s0 + s1) + (s2 + s3);
}

// Epilogue d-slice for wave W (compile-time so zv[] indexing stays in registers).
template <int W>
__device__ __forceinline__ float epi_slice(const float* __restrict__ cbest,
                                           float* __restrict__ qrow,
                                           const float (&zv)[ND]) {
    float l0 = 0.f, l1 = 0.f, l2 = 0.f, l3 = 0.f;
#pragma unroll
    for (int i = 0; i < 4; i++) {
        float4 c = reinterpret_cast<const float4*>(cbest)[W * 4 + i];
        float zx = zv[W * 16 + 4 * i + 0], zy = zv[W * 16 + 4 * i + 1];
        float zz = zv[W * 16 + 4 * i + 2], zw = zv[W * 16 + 4 * i + 3];
        float4 st;
        st.x = zx + (c.x - zx);
        st.y = zy + (c.y - zy);
        st.z = zz + (c.z - zz);
        st.w = zw + (c.w - zw);
        reinterpret_cast<float4*>(qrow)[W * 4 + i] = st;
        float dx = zx - c.x, dy = zy - c.y, dz = zz - c.z, dw = zw - c.w;
        l0 = fmaf(dx, dx, l0); l1 = fmaf(dy, dy, l1);
        l2 = fmaf(dz, dz, l2); l3 = fmaf(dw, dw, l3);
    }
    return (l0 + l1) + (l2 + l3);
}

// Rolling VMEM pipeline: 4 quarter-codeword buffers (A..D), each 4x float4.
// Compute quarter X of codeword k, then issue loads of quarter X of k+1.
// WAR register deps enforce the pipeline; compiler emits counted vmcnt waits.
// NOTE: (Q##N).x parenthesization is required — `N.x` would lex as one
// pp-number token and break the paste.
#define DECLQ(Q) float4 Q##0, Q##1, Q##2, Q##3;
#define LOADQ(Q, kk, qq) { \
    const float4* _p = reinterpret_cast<const float4*>( \
        cbase + ((size_t)(kk) << 8) + ((qq) << 6)); \
    Q##0 = _p[0]; Q##1 = _p[1]; Q##2 = _p[2]; Q##3 = _p[3]; }
#define FMAQ(Q, qq) \
    a0 = fmaf(zv[(qq)*16+ 0], (Q##0).x, a0); a1 = fmaf(zv[(qq)*16+ 1], (Q##0).y, a1); \
    a2 = fmaf(zv[(qq)*16+ 2], (Q##0).z, a2); a3 = fmaf(zv[(qq)*16+ 3], (Q##0).w, a3); \
    a0 = fmaf(zv[(qq)*16+ 4], (Q##1).x, a0); a1 = fmaf(zv[(qq)*16+ 5], (Q##1).y, a1); \
    a2 = fmaf(zv[(qq)*16+ 6], (Q##1).z, a2); a3 = fmaf(zv[(qq)*16+ 7], (Q##1).w, a3); \
    a0 = fmaf(zv[(qq)*16+ 8], (Q##2).x, a0); a1 = fmaf(zv[(qq)*16+ 9], (Q##2).y, a1); \
    a2 = fmaf(zv[(qq)*16+10], (Q##2).z, a2); a3 = fmaf(zv[(qq)*16+11], (Q##2).w, a3); \
    a0 = fmaf(zv[(qq)*16+12], (Q##3).x, a0); a1 = fmaf(zv[(qq)*16+13], (Q##3).y, a1); \
    a2 = fmaf(zv[(qq)*16+14], (Q##3).z, a2); a3 = fmaf(zv[(qq)*16+15], (Q##3).w, a3);

// Block = 4 waves over the same 64 batch rows of one group; wave w scans
// codewords [w*256,(w+1)*256) via the VMEM pipeline. Lane = row.
__global__ __launch_bounds__(256, 3) void vq_main(
        const float* __restrict__ z, const float* __restrict__ cb,
        const float* __restrict__ c2, float* __restrict__ qout,
        float* __restrict__ idxout, int* __restrict__ counts,
        float* __restrict__ losssum) {
    const int tid = threadIdx.x;
    const int lane = tid & 63;
    const int wu = __builtin_amdgcn_readfirstlane(tid >> 6);  // wave id, uniform
    const int g = blockIdx.x >> 6;        // 64 consecutive blocks share a group
    const int rowblk = blockIdx.x & 63;   // -> same 256KB codebook slab in L2
    const int row = rowblk * 64 + lane;

    const float* zrow = z + (size_t)row * (NG * ND) + (size_t)g * ND;
    float zv[ND];
#pragma unroll
    for (int i = 0; i < ND / 4; i++) {
        float4 v = reinterpret_cast<const float4*>(zrow)[i];
        zv[4 * i + 0] = v.x; zv[4 * i + 1] = v.y;
        zv[4 * i + 2] = v.z; zv[4 * i + 3] = v.w;
    }
    float t0 = 0.f, t1 = 0.f, t2 = 0.f, t3 = 0.f;
#pragma unroll
    for (int d = 0; d < ND; d += 4) {
        t0 = fmaf(zv[d + 0], zv[d + 0], t0);
        t1 = fmaf(zv[d + 1], zv[d + 1], t1);
        t2 = fmaf(zv[d + 2], zv[d + 2], t2);
        t3 = fmaf(zv[d + 3], zv[d + 3], t3);
    }
    const float z2 = (t0 + t1) + (t2 + t3);

    const float* cg = cb + (size_t)g * NK * ND;

    // Opaque VGPR zero: compiler cannot prove the address wave-uniform, so the
    // codebook stream stays on VMEM (in-order, vmcnt-pipelined) not s_load.
    int vzero;
    asm volatile("v_mov_b32 %0, 0" : "=v"(vzero));
    const char* cbase = (const char*)cg + vzero;
    const char* c2base = (const char*)(c2 + (size_t)g * NK) + vzero;

    const int k0 = wu * KCHUNK;           // uniform per wave

    DECLQ(A) DECLQ(B) DECLQ(C) DECLQ(D)
    LOADQ(A, k0, 0) LOADQ(B, k0, 1) LOADQ(C, k0, 2) LOADQ(D, k0, 3)
    float c2cur = *reinterpret_cast<const float*>(c2base + 4 * (size_t)k0);

    float best = 3.402823466e38f;
    int bestk = k0;
#pragma unroll 1
    for (int k = k0; k < k0 + KCHUNK; k++) {
        int kn = k + 1;
        if (kn == k0 + KCHUNK) kn = k0;   // clamp: last iter reloads k0 (unused)
        float c2nxt = *reinterpret_cast<const float*>(c2base + 4 * (size_t)kn);
        float a0 = 0.f, a1 = 0.f, a2 = 0.f, a3 = 0.f;
        FMAQ(A, 0) LOADQ(A, kn, 0)
        FMAQ(B, 1) LOADQ(B, kn, 1)
        FMAQ(C, 2) LOADQ(C, kn, 2)
        FMAQ(D, 3) LOADQ(D, kn, 3)
        float zc = (a0 + a1) + (a2 + a3);
        float dist = (z2 - 2.0f * zc) + c2cur;   // identical fp ops to passing ver
        if (dist < best) { best = dist; bestk = k; }  // strict < == first-min ties
        c2cur = c2nxt;
    }

    // Combine per-lane argmin across the 4 k-ranges (fold in wave order).
    __shared__ float s_best[KSPLIT][64];
    __shared__ int s_bk[KSPLIT][64];
    __shared__ int s_win[64];
    s_best[wu][lane] = best;
    s_bk[wu][lane] = bestk;
    __syncthreads();
    if (wu == 0) {
        float b = s_best[0][lane];
        int bk = s_bk[0][lane];
#pragma unroll
        for (int q = 1; q < KSPLIT; q++) {
            float d = s_best[q][lane];
            int kk = s_bk[q][lane];
            if (d < b) { b = d; bk = kk; }
        }
        s_win[lane] = bk;
        idxout[(size_t)row * NG + g] = (float)bk;
        atomicAdd(&counts[bk], 1);
    }
    __syncthreads();

    const int bk = s_win[lane];
    const float* cbest = cg + (size_t)bk * ND;   // divergent per lane
    float* qrow = qout + (size_t)row * (NG * ND) + (size_t)g * ND;
    float lsum;
    switch (wu) {
        case 0: lsum = epi_slice<0>(cbest, qrow, zv); break;
        case 1: lsum = epi_slice<1>(cbest, qrow, zv); break;
        case 2: lsum = epi_slice<2>(cbest, qrow, zv); break;
        default: lsum = epi_slice<3>(cbest, qrow, zv); break;
    }
#pragma unroll
    for (int off = 32; off > 0; off >>= 1) lsum += __shfl_down(lsum, off, 64);
    if (lane == 0) atomicAdd(losssum, lsum);
}

__global__ void vq_final(const int* __restrict__ counts,
                         const float* __restrict__ losssum,
                         float* __restrict__ out) {
    __shared__ float red[256];
    int tid = threadIdx.x;
    float e = 0.f;
    for (int k = tid; k < NK; k += 256) {
        float u = (float)counts[k] * (1.0f / 131072.0f);
        e -= u * logf(u + 1e-10f);
    }
    red[tid] = e;
    __syncthreads();
    for (int s = 128; s > 0; s >>= 1) {
        if (tid < s) red[tid] += red[tid + s];
        __syncthreads();
    }
    if (tid == 0) {
        float loss = *losssum * (1.0f / 8388608.0f);
        float ent = red[0];
        out[0] = loss;      // commitment_loss
        out[1] = loss;      // codebook_loss (forward-identical)
        out[2] = ent;       // entropy
        out[3] = expf(ent); // perplexity
    }
}

extern "C" void kernel_launch(void* const* d_in, const int* in_sizes, int n_in,
                              void* d_out, int out_size, void* d_ws, size_t ws_size,
                              hipStream_t stream) {
    const float* z = (const float*)d_in[0];
    const float* cb = (const float*)d_in[1];
    float* out = (float*)d_out;
    float* qout = out;                                  // 8388608
    float* idxout = out + (size_t)NB * NG * ND;         // +131072
    float* scal = idxout + (size_t)NB * NG;             // 4 scalars

    float* c2 = (float*)d_ws;
    int* counts = (int*)(c2 + NG * NK);
    float* losssum = (float*)(counts + NK);

    vq_c2<<<(NG * NK + 255) / 256, 256, 0, stream>>>(cb, c2, counts, losssum);
    vq_main<<<NG * (NB / 64), 256, 0, stream>>>(z, cb, c2, qout, idxout, counts, losssum);
    vq_final<<<1, 256, 0, stream>>>(counts, losssum, scal);
}

// Round 12
// 508.579 us; speedup vs baseline: 2.0967x; 2.0967x over previous
//
#include <hip/hip_runtime.h>
#include <math.h>

#define NG 32
#define NK 1024
#define ND 64
#define NB 4096
#define TILE 16
#define NT (NK / TILE)

// ws layout (floats): [0 .. NG*NK) c2 | counts(int)[NK] | loss sum

// c2 precompute + buffer init fused (disjoint writes, both done before vq_main).
__global__ void vq_c2(const float* __restrict__ cb, float* __restrict__ c2,
                      int* __restrict__ counts, float* __restrict__ losssum) {
    int i = blockIdx.x * blockDim.x + threadIdx.x;
    if (i < NK) counts[i] = 0;
    if (i == 0) *losssum = 0.f;
    if (i >= NG * NK) return;
    const float* c = cb + (size_t)i * ND;
    float s0 = 0.f, s1 = 0.f, s2 = 0.f, s3 = 0.f;
#pragma unroll
    for (int d = 0; d < ND; d += 4) {
        float4 v = *reinterpret_cast<const float4*>(c + d);
        s0 = fmaf(v.x, v.x, s0);
        s1 = fmaf(v.y, v.y, s1);
        s2 = fmaf(v.z, v.z, s2);
        s3 = fmaf(v.w, v.w, s3);
    }
    c2[i] = (s0 + s1) + (s2 + s3);
}

// Block = 256 threads = 256 distinct batch rows of one group. All threads scan
// all 1024 codewords from double-buffered LDS tiles (16 codewords = 4KB each).
// Wave-uniform LDS reads broadcast (no conflicts, no scalar-unit serialization,
// no per-thread codeword registers -> no spill).
__global__ __launch_bounds__(256) void vq_main(
        const float* __restrict__ z, const float* __restrict__ cb,
        const float* __restrict__ c2, float* __restrict__ qout,
        float* __restrict__ idxout, int* __restrict__ counts,
        float* __restrict__ losssum) {
    const int tid = threadIdx.x;
    const int g = blockIdx.x >> 4;         // 16 consecutive blocks per group
    const int rowchunk = blockIdx.x & 15;
    const int row = rowchunk * 256 + tid;

    // This thread's 64-dim z slice in registers.
    const float* zrow = z + (size_t)row * (NG * ND) + (size_t)g * ND;
    float zv[ND];
#pragma unroll
    for (int i = 0; i < ND / 4; i++) {
        float4 v = reinterpret_cast<const float4*>(zrow)[i];
        zv[4 * i + 0] = v.x; zv[4 * i + 1] = v.y;
        zv[4 * i + 2] = v.z; zv[4 * i + 3] = v.w;
    }
    float t0 = 0.f, t1 = 0.f, t2 = 0.f, t3 = 0.f;
#pragma unroll
    for (int d = 0; d < ND; d += 4) {
        t0 = fmaf(zv[d + 0], zv[d + 0], t0);
        t1 = fmaf(zv[d + 1], zv[d + 1], t1);
        t2 = fmaf(zv[d + 2], zv[d + 2], t2);
        t3 = fmaf(zv[d + 3], zv[d + 3], t3);
    }
    const float z2 = (t0 + t1) + (t2 + t3);

    const float* cg = cb + (size_t)g * NK * ND;
    const float* c2g = c2 + (size_t)g * NK;

    __shared__ float buf[2][TILE * ND];    // 2 x 4KB codeword tiles
    __shared__ float c2s[2][TILE];

    // Prologue: stage tile 0. (TILE*ND = 1024 floats = 256 float4 = 1/thread.)
    float4 streg = reinterpret_cast<const float4*>(cg)[tid];
    float c2reg = (tid < TILE) ? c2g[tid] : 0.f;
    reinterpret_cast<float4*>(buf[0])[tid] = streg;
    if (tid < TILE) c2s[0][tid] = c2reg;
    __syncthreads();

    float best = 3.402823466e38f;
    int bestk = 0;
#pragma unroll 1
    for (int t = 0; t < NT; t++) {
        const int p = t & 1;
        const bool has_next = (t + 1 < NT);
        if (has_next) {  // issue next-tile loads early; latency hides under compute
            streg = reinterpret_cast<const float4*>(cg + (size_t)(t + 1) * TILE * ND)[tid];
            if (tid < TILE) c2reg = c2g[(t + 1) * TILE + tid];
        }
        const float* bp = buf[p];
#pragma unroll 4
        for (int kk = 0; kk < TILE; kk++) {
            const float4* cw = reinterpret_cast<const float4*>(bp + kk * ND);
            float a0 = 0.f, a1 = 0.f, a2 = 0.f, a3 = 0.f;
#pragma unroll
            for (int j = 0; j < 16; j++) {
                float4 cq = cw[j];  // wave-uniform LDS address -> broadcast
                a0 = fmaf(zv[4 * j + 0], cq.x, a0);
                a1 = fmaf(zv[4 * j + 1], cq.y, a1);
                a2 = fmaf(zv[4 * j + 2], cq.z, a2);
                a3 = fmaf(zv[4 * j + 3], cq.w, a3);
            }
            float zc = (a0 + a1) + (a2 + a3);
            float dist = (z2 - 2.0f * zc) + c2s[p][kk];  // identical op order
            int k = t * TILE + kk;
            if (dist < best) { best = dist; bestk = k; }  // strict < first-min
        }
        if (has_next) {
            reinterpret_cast<float4*>(buf[p ^ 1])[tid] = streg;  // waits vmcnt
            if (tid < TILE) c2s[p ^ 1][tid] = c2reg;
        }
        __syncthreads();  // one barrier/tile: orders write(p^1) vs next reads
    }

    // Epilogue (round-1 verified structure): gather winning code, write
    // z + (zq - z), accumulate (z - zq)^2.
    const float* cbest = cg + (size_t)bestk * ND;  // divergent per lane
    float* qrow = qout + (size_t)row * (NG * ND) + (size_t)g * ND;
    float l0 = 0.f, l1 = 0.f, l2 = 0.f, l3 = 0.f;
#pragma unroll
    for (int i = 0; i < ND / 4; i++) {
        float4 c = reinterpret_cast<const float4*>(cbest)[i];
        float zx = zv[4 * i + 0], zy = zv[4 * i + 1];
        float zz = zv[4 * i + 2], zw = zv[4 * i + 3];
        float4 st;
        st.x = zx + (c.x - zx);
        st.y = zy + (c.y - zy);
        st.z = zz + (c.z - zz);
        st.w = zw + (c.w - zw);
        reinterpret_cast<float4*>(qrow)[i] = st;
        float dx = zx - c.x, dy = zy - c.y, dz = zz - c.z, dw = zw - c.w;
        l0 = fmaf(dx, dx, l0); l1 = fmaf(dy, dy, l1);
        l2 = fmaf(dz, dz, l2); l3 = fmaf(dw, dw, l3);
    }
    float lsum = (l0 + l1) + (l2 + l3);

    idxout[(size_t)row * NG + g] = (float)bestk;
    atomicAdd(&counts[bestk], 1);

#pragma unroll
    for (int off = 32; off > 0; off >>= 1) lsum += __shfl_down(lsum, off, 64);
    if ((tid & 63) == 0) atomicAdd(losssum, lsum);
}

__global__ void vq_final(const int* __restrict__ counts,
                         const float* __restrict__ losssum,
                         float* __restrict__ out) {
    __shared__ float red[256];
    int tid = threadIdx.x;
    float e = 0.f;
    for (int k = tid; k < NK; k += 256) {
        float u = (float)counts[k] * (1.0f / 131072.0f);
        e -= u * logf(u + 1e-10f);
    }
    red[tid] = e;
    __syncthreads();
    for (int s = 128; s > 0; s >>= 1) {
        if (tid < s) red[tid] += red[tid + s];
        __syncthreads();
    }
    if (tid == 0) {
        float loss = *losssum * (1.0f / 8388608.0f);
        float ent = red[0];
        out[0] = loss;      // commitment_loss
        out[1] = loss;      // codebook_loss (forward-identical)
        out[2] = ent;       // entropy
        out[3] = expf(ent); // perplexity
    }
}

extern "C" void kernel_launch(void* const* d_in, const int* in_sizes, int n_in,
                              void* d_out, int out_size, void* d_ws, size_t ws_size,
                              hipStream_t stream) {
    const float* z = (const float*)d_in[0];
    const float* cb = (const float*)d_in[1];
    float* out = (float*)d_out;
    float* qout = out;                                  // 8388608
    float* idxout = out + (size_t)NB * NG * ND;         // +131072
    float* scal = idxout + (size_t)NB * NG;             // 4 scalars

    float* c2 = (float*)d_ws;
    int* counts = (int*)(c2 + NG * NK);
    float* losssum = (float*)(counts + NK);

    vq_c2<<<(NG * NK + 255) / 256, 256, 0, stream>>>(cb, c2, counts, losssum);
    vq_main<<<NG * (NB / 256), 256, 0, stream>>>(z, cb, c2, qout, idxout, counts, losssum);
    vq_final<<<1, 256, 0, stream>>>(counts, losssum, scal);
}

// Round 16
// 422.433 us; speedup vs baseline: 2.5242x; 1.2039x over previous
//
#include <hip/hip_runtime.h>
#include <math.h>

#define NG 32
#define NK 1024
#define ND 64
#define NB 4096
#define TILE 16
#define NT (NK / TILE)

// ws layout (floats): [0 .. NG*NK) c2 | counts(int)[NK] | loss sum

__global__ void vq_c2(const float* __restrict__ cb, float* __restrict__ c2,
                      int* __restrict__ counts, float* __restrict__ losssum) {
    int i = blockIdx.x * blockDim.x + threadIdx.x;
    if (i < NK) counts[i] = 0;
    if (i == 0) *losssum = 0.f;
    if (i >= NG * NK) return;
    const float* c = cb + (size_t)i * ND;
    float s0 = 0.f, s1 = 0.f, s2 = 0.f, s3 = 0.f;
#pragma unroll
    for (int d = 0; d < ND; d += 4) {
        float4 v = *reinterpret_cast<const float4*>(c + d);
        s0 = fmaf(v.x, v.x, s0);
        s1 = fmaf(v.y, v.y, s1);
        s2 = fmaf(v.z, v.z, s2);
        s3 = fmaf(v.w, v.w, s3);
    }
    c2[i] = (s0 + s1) + (s2 + s3);
}

// R=2 rows/thread: one LDS codeword read feeds 8 FMAs (was 4) -> DS-pipe
// instruction count halves (the measured bottleneck: ~9cyc/ds_read_b128,
// 128/k/CU at R=1 = 1137cyc/k). Block = 128 threads x 2 rows = 256 rows of
// one group; grid 512 (2 blocks/CU). Codebook in double-buffered LDS tiles,
// wave-uniform broadcast reads.
__global__ __launch_bounds__(128, 1) void vq_main(
        const float* __restrict__ z, const float* __restrict__ cb,
        const float* __restrict__ c2, float* __restrict__ qout,
        float* __restrict__ idxout, int* __restrict__ counts,
        float* __restrict__ losssum) {
    const int tid = threadIdx.x;
    const int g = blockIdx.x >> 4;         // 16 consecutive blocks per group
    const int rowchunk = blockIdx.x & 15;
    const int row0 = rowchunk * 256 + tid;
    const int row1 = row0 + 128;

    // Two 64-dim z slices in registers.
    const float* zr0 = z + (size_t)row0 * (NG * ND) + (size_t)g * ND;
    const float* zr1 = z + (size_t)row1 * (NG * ND) + (size_t)g * ND;
    float zv0[ND], zv1[ND];
#pragma unroll
    for (int i = 0; i < ND / 4; i++) {
        float4 v = reinterpret_cast<const float4*>(zr0)[i];
        zv0[4 * i + 0] = v.x; zv0[4 * i + 1] = v.y;
        zv0[4 * i + 2] = v.z; zv0[4 * i + 3] = v.w;
        float4 w = reinterpret_cast<const float4*>(zr1)[i];
        zv1[4 * i + 0] = w.x; zv1[4 * i + 1] = w.y;
        zv1[4 * i + 2] = w.z; zv1[4 * i + 3] = w.w;
    }
    float t00 = 0.f, t01 = 0.f, t02 = 0.f, t03 = 0.f;
    float t10 = 0.f, t11 = 0.f, t12 = 0.f, t13 = 0.f;
#pragma unroll
    for (int d = 0; d < ND; d += 4) {
        t00 = fmaf(zv0[d + 0], zv0[d + 0], t00);
        t01 = fmaf(zv0[d + 1], zv0[d + 1], t01);
        t02 = fmaf(zv0[d + 2], zv0[d + 2], t02);
        t03 = fmaf(zv0[d + 3], zv0[d + 3], t03);
        t10 = fmaf(zv1[d + 0], zv1[d + 0], t10);
        t11 = fmaf(zv1[d + 1], zv1[d + 1], t11);
        t12 = fmaf(zv1[d + 2], zv1[d + 2], t12);
        t13 = fmaf(zv1[d + 3], zv1[d + 3], t13);
    }
    const float z2_0 = (t00 + t01) + (t02 + t03);
    const float z2_1 = (t10 + t11) + (t12 + t13);

    const float* cg = cb + (size_t)g * NK * ND;
    const float* c2g = c2 + (size_t)g * NK;

    __shared__ float buf[2][TILE * ND];    // 2 x 4KB codeword tiles
    __shared__ float c2s[2][TILE];

    // Prologue: stage tile 0 (1024 floats = 256 float4 = 2/thread).
    float4 sa = reinterpret_cast<const float4*>(cg)[tid];
    float4 sb = reinterpret_cast<const float4*>(cg)[tid + 128];
    float c2reg = (tid < TILE) ? c2g[tid] : 0.f;
    reinterpret_cast<float4*>(buf[0])[tid] = sa;
    reinterpret_cast<float4*>(buf[0])[tid + 128] = sb;
    if (tid < TILE) c2s[0][tid] = c2reg;
    __syncthreads();

    float best0 = 3.402823466e38f, best1 = 3.402823466e38f;
    int bestk0 = 0, bestk1 = 0;
#pragma unroll 1
    for (int t = 0; t < NT; t++) {
        const int p = t & 1;
        const bool has_next = (t + 1 < NT);
        if (has_next) {  // issue next-tile loads early; latency hides under compute
            const float4* src = reinterpret_cast<const float4*>(
                cg + (size_t)(t + 1) * TILE * ND);
            sa = src[tid];
            sb = src[tid + 128];
            if (tid < TILE) c2reg = c2g[(t + 1) * TILE + tid];
        }
        const float* bp = buf[p];
#pragma unroll 4
        for (int kk = 0; kk < TILE; kk++) {
            const float4* cw = reinterpret_cast<const float4*>(bp + kk * ND);
            float a00 = 0.f, a01 = 0.f, a02 = 0.f, a03 = 0.f;
            float a10 = 0.f, a11 = 0.f, a12 = 0.f, a13 = 0.f;
#pragma unroll
            for (int j = 0; j < 16; j++) {
                float4 cq = cw[j];  // wave-uniform LDS address -> broadcast
                a00 = fmaf(zv0[4 * j + 0], cq.x, a00);
                a01 = fmaf(zv0[4 * j + 1], cq.y, a01);
                a02 = fmaf(zv0[4 * j + 2], cq.z, a02);
                a03 = fmaf(zv0[4 * j + 3], cq.w, a03);
                a10 = fmaf(zv1[4 * j + 0], cq.x, a10);
                a11 = fmaf(zv1[4 * j + 1], cq.y, a11);
                a12 = fmaf(zv1[4 * j + 2], cq.z, a12);
                a13 = fmaf(zv1[4 * j + 3], cq.w, a13);
            }
            float zc0 = (a00 + a01) + (a02 + a03);
            float zc1 = (a10 + a11) + (a12 + a13);
            float c2k = c2s[p][kk];
            float dist0 = (z2_0 - 2.0f * zc0) + c2k;   // identical op order
            float dist1 = (z2_1 - 2.0f * zc1) + c2k;
            int k = t * TILE + kk;
            if (dist0 < best0) { best0 = dist0; bestk0 = k; }  // strict <
            if (dist1 < best1) { best1 = dist1; bestk1 = k; }
        }
        if (has_next) {
            reinterpret_cast<float4*>(buf[p ^ 1])[tid] = sa;   // waits vmcnt
            reinterpret_cast<float4*>(buf[p ^ 1])[tid + 128] = sb;
            if (tid < TILE) c2s[p ^ 1][tid] = c2reg;
        }
        __syncthreads();  // one barrier/tile: orders write(p^1) vs next reads
    }

    // Epilogue: gather winning codes, write z + (zq - z), accumulate (z-zq)^2.
    float lsum = 0.f;
    {
        const float* cbest = cg + (size_t)bestk0 * ND;
        float* qrow = qout + (size_t)row0 * (NG * ND) + (size_t)g * ND;
        float l0 = 0.f, l1 = 0.f, l2 = 0.f, l3 = 0.f;
#pragma unroll
        for (int i = 0; i < ND / 4; i++) {
            float4 c = reinterpret_cast<const float4*>(cbest)[i];
            float zx = zv0[4 * i + 0], zy = zv0[4 * i + 1];
            float zz = zv0[4 * i + 2], zw = zv0[4 * i + 3];
            float4 st;
            st.x = zx + (c.x - zx);
            st.y = zy + (c.y - zy);
            st.z = zz + (c.z - zz);
            st.w = zw + (c.w - zw);
            reinterpret_cast<float4*>(qrow)[i] = st;
            float dx = zx - c.x, dy = zy - c.y, dz = zz - c.z, dw = zw - c.w;
            l0 = fmaf(dx, dx, l0); l1 = fmaf(dy, dy, l1);
            l2 = fmaf(dz, dz, l2); l3 = fmaf(dw, dw, l3);
        }
        lsum += (l0 + l1) + (l2 + l3);
    }
    {
        const float* cbest = cg + (size_t)bestk1 * ND;
        float* qrow = qout + (size_t)row1 * (NG * ND) + (size_t)g * ND;
        float l0 = 0.f, l1 = 0.f, l2 = 0.f, l3 = 0.f;
#pragma unroll
        for (int i = 0; i < ND / 4; i++) {
            float4 c = reinterpret_cast<const float4*>(cbest)[i];
            float zx = zv1[4 * i + 0], zy = zv1[4 * i + 1];
            float zz = zv1[4 * i + 2], zw = zv1[4 * i + 3];
            float4 st;
            st.x = zx + (c.x - zx);
            st.y = zy + (c.y - zy);
            st.z = zz + (c.z - zz);
            st.w = zw + (c.w - zw);
            reinterpret_cast<float4*>(qrow)[i] = st;
            float dx = zx - c.x, dy = zy - c.y, dz = zz - c.z, dw = zw - c.w;
            l0 = fmaf(dx, dx, l0); l1 = fmaf(dy, dy, l1);
            l2 = fmaf(dz, dz, l2); l3 = fmaf(dw, dw, l3);
        }
        lsum += (l0 + l1) + (l2 + l3);
    }

    idxout[(size_t)row0 * NG + g] = (float)bestk0;
    idxout[(size_t)row1 * NG + g] = (float)bestk1;
    atomicAdd(&counts[bestk0], 1);
    atomicAdd(&counts[bestk1], 1);

#pragma unroll
    for (int off = 32; off > 0; off >>= 1) lsum += __shfl_down(lsum, off, 64);
    if ((tid & 63) == 0) atomicAdd(losssum, lsum);
}

__global__ void vq_final(const int* __restrict__ counts,
                         const float* __restrict__ losssum,
                         float* __restrict__ out) {
    __shared__ float red[256];
    int tid = threadIdx.x;
    float e = 0.f;
    for (int k = tid; k < NK; k += 256) {
        float u = (float)counts[k] * (1.0f / 131072.0f);
        e -= u * logf(u + 1e-10f);
    }
    red[tid] = e;
    __syncthreads();
    for (int s = 128; s > 0; s >>= 1) {
        if (tid < s) red[tid] += red[tid + s];
        __syncthreads();
    }
    if (tid == 0) {
        float loss = *losssum * (1.0f / 8388608.0f);
        float ent = red[0];
        out[0] = loss;      // commitment_loss
        out[1] = loss;      // codebook_loss (forward-identical)
        out[2] = ent;       // entropy
        out[3] = expf(ent); // perplexity
    }
}

extern "C" void kernel_launch(void* const* d_in, const int* in_sizes, int n_in,
                              void* d_out, int out_size, void* d_ws, size_t ws_size,
                              hipStream_t stream) {
    const float* z = (const float*)d_in[0];
    const float* cb = (const float*)d_in[1];
    float* out = (float*)d_out;
    float* qout = out;                                  // 8388608
    float* idxout = out + (size_t)NB * NG * ND;         // +131072
    float* scal = idxout + (size_t)NB * NG;             // 4 scalars

    float* c2 = (float*)d_ws;
    int* counts = (int*)(c2 + NG * NK);
    float* losssum = (float*)(counts + NK);

    vq_c2<<<(NG * NK + 255) / 256, 256, 0, stream>>>(cb, c2, counts, losssum);
    vq_main<<<NG * (NB / 256), 128, 0, stream>>>(z, cb, c2, qout, idxout, counts, losssum);
    vq_final<<<1, 256, 0, stream>>>(counts, losssum, scal);
}